// Round 7
// baseline (196.791 us; speedup 1.0000x reference)
//
#include <hip/hip_runtime.h>

// Multi-kernel EM split, round 7: maximize RESIDENT waves/CU.
// Shapes (fp32): x(8,14,14,32,16) a(8,14,14,32) W(288,32,16) bu(32) ba(32);
// out: p_out 147456 + a_out 9216.
// History: 512-thr monolith (r2) = 96us, VALUBusy 23%, Occ 13%. Split-4 with
// 512-thr blocks (r6) = 44us/iter, VALUBusy 26%, Occ 31% — latency-bound, waves
// don't fit. r3-r5: compiler forces 64 VGPR on 512-thr blocks and spills.
// Fix: EMBRACE 64 VGPR — halve per-thread state by splitting p across lanes.
// Wave = 1 n x (2 p-halves x 32 c). Block = 256 thr = 4 n-slices. Grid =
// 288 pos x 8 n-splits = 2304 blocks -> ~8 blocks/CU, ~32 waves/CU.

#define NPOS 288
#define NS   8                // n-splits per position
#define NB   36               // n per block (288/8)
#define ASTR 33               // per-(pos,c) acc/tabs stride: 16 + 16 + 1
#define ACC_FLOATS ((size_t)NPOS * 32 * ASTR)

// ---------------- stats: one EM iteration's fused E+M pass ----------------
// grid 2304 = pos*8 + split; block 256: c=tid&31, h=(tid>>5)&1 (l-half),
// s=tid>>6 (n-slice = wave). Thread owns p in {4i + 2h + l'} (8 of 16).
template <bool FIRST>
__global__ __launch_bounds__(256) void stats_kernel(
    const float* __restrict__ xg,
    const float* __restrict__ ag,
    const float* __restrict__ wg,
    const float* __restrict__ tabs,   // [pos][c][33]: A[16] B[16] Kc
    float* __restrict__ acc)          // [pos][c][33]: m[16] v[16] rs
{
    __shared__ __align__(16) float pose_s[NB * 16];   // 2.3 KB
    __shared__ float a_s[NB];
    __shared__ float scratch_m[4 * 32 * 17];          // [s][c][17]: 16 p + pad (2-way ok)
    __shared__ float scratch_v[4 * 32 * 17];
    __shared__ float rsum_part[4 * 32];

    const int tid   = threadIdx.x;
    const int blk   = blockIdx.x;
    const int pos   = blk >> 3;
    const int nbase = (blk & 7) * NB;
    const int bb  = pos / 36;
    const int rem = pos % 36;
    const int yy  = rem / 6;
    const int xx  = rem % 6;

    // ---- stage this block's 36 pose rows (+ a_in) into LDS ----
    for (int i = tid; i < NB * 16; i += 256) {
        const int nl = i >> 4, off = i & 15;
        const int n  = nbase + nl;
        const int wi = n >> 5, bi = n & 31;
        const int kh = wi / 3, kw = wi % 3;
        pose_s[i] = xg[((size_t)(((bb * 14) + (2 * yy + kh)) * 14 + (2 * xx + kw)) * 32 + bi) * 16 + off];
    }
    if (tid < NB) {
        const int n  = nbase + tid;
        const int wi = n >> 5, bi = n & 31;
        const int kh = wi / 3, kw = wi % 3;
        a_s[tid] = ag[(size_t)(((bb * 14) + (2 * yy + kh)) * 14 + (2 * xx + kw)) * 32 + bi];
    }
    __syncthreads();

    const int c = tid & 31;          // capsule-out index
    const int h = (tid >> 5) & 1;    // l-half: this thread's l = 2h + l'
    const int s = tid >> 6;          // n-slice = wave 0..3

    // hoisted per-c routing state for OWN 8 p only: p = 4i + 2h + l'
    float A_c[8], B_c[8], Kc = 0.f;
    if (!FIRST) {
        const float* tb = tabs + ((size_t)pos * 32 + c) * ASTR;
        #pragma unroll
        for (int i = 0; i < 4; ++i)
            #pragma unroll
            for (int l = 0; l < 2; ++l) {
                A_c[i * 2 + l] = tb[4 * i + 2 * h + l];
                B_c[i * 2 + l] = tb[16 + 4 * i + 2 * h + l];
            }
        Kc = tb[32];
    }
    float macc[8], vacc[8], rs = 0.f;
    #pragma unroll
    for (int p = 0; p < 8; ++p) { macc[p] = 0.f; vacc[p] = 0.f; }

    // ---- fused E+M: 9 n per thread (n_local = 4k + s), whole wave same n ----
    #pragma unroll 1
    for (int k = 0; k < 9; ++k) {
        const int nl = k * 4 + s;
        const int n  = nbase + nl;
        // pose (broadcast to all lanes)
        const float4* pp = (const float4*)&pose_s[nl << 4];
        float pf[16];
        float4 q;
        q = pp[0]; pf[0]=q.x;  pf[1]=q.y;  pf[2]=q.z;  pf[3]=q.w;
        q = pp[1]; pf[4]=q.x;  pf[5]=q.y;  pf[6]=q.z;  pf[7]=q.w;
        q = pp[2]; pf[8]=q.x;  pf[9]=q.y;  pf[10]=q.z; pf[11]=q.w;
        q = pp[3]; pf[12]=q.x; pf[13]=q.y; pf[14]=q.z; pf[15]=q.w;
        // W: this thread needs W[n][c][j*4 + 2h + l'] for j=0..3, l'=0..1 (32 B)
        const float2* wq = (const float2*)wg + ((size_t)(n * 32 + c) * 8 + h);
        float2 wj0 = wq[0], wj1 = wq[2], wj2 = wq[4], wj3 = wq[6];
        // v[i][l'] = sum_j pose[i][j] * W[j][2h+l'], own 8 of 16 p
        float v[8];
        #pragma unroll
        for (int i = 0; i < 4; ++i) {
            v[i*2+0] = fmaf(pf[i*4+0], wj0.x, fmaf(pf[i*4+1], wj1.x,
                        fmaf(pf[i*4+2], wj2.x, pf[i*4+3] * wj3.x)));
            v[i*2+1] = fmaf(pf[i*4+0], wj0.y, fmaf(pf[i*4+1], wj1.y,
                        fmaf(pf[i*4+2], wj2.y, pf[i*4+3] * wj3.y)));
        }
        float r;
        if (FIRST) {
            r = a_s[nl] * 0.03125f;   // (1/C)*a_in — c-uniform, no softmax
        } else {
            float t = 0.f;
            #pragma unroll
            for (int p = 0; p < 8; ++p)
                t = fmaf(fmaf(v[p], A_c[p], -B_c[p]), v[p], t);
            t += __shfl_xor(t, 32);            // combine the two p-halves
            float lnap = -t - Kc;
            // softmax over the 32 c-lanes (both halves hold identical values)
            float m = lnap;
            #pragma unroll
            for (int msk = 16; msk >= 1; msk >>= 1) m = fmaxf(m, __shfl_xor(m, msk));
            float e = __expf(lnap - m);
            float sum = e;
            #pragma unroll
            for (int msk = 16; msk >= 1; msk >>= 1) sum += __shfl_xor(sum, msk);
            r = e / sum;
        }
        rs += r;
        #pragma unroll
        for (int p = 0; p < 8; ++p) {
            float rv = r * v[p];
            macc[p] = fmaf(r, v[p], macc[p]);
            vacc[p] = fmaf(rv, v[p], vacc[p]);
        }
    }

    // ---- per-wave scratch write: lanes cover full 16 p across the 2 halves ----
    {
        const int base = (s * 32 + c) * 17;
        #pragma unroll
        for (int i = 0; i < 4; ++i)
            #pragma unroll
            for (int l = 0; l < 2; ++l) {
                scratch_m[base + 4 * i + 2 * h + l] = macc[i * 2 + l];
                scratch_v[base + 4 * i + 2 * h + l] = vacc[i * 2 + l];
            }
        if (h == 0) rsum_part[s * 32 + c] = rs;
    }
    __syncthreads();

    // ---- final: 256 thr = 32 c x 8 q; each sums 2 p over 4 slices, atomics ----
    const int fc = tid >> 3, fq = tid & 7;
    float m0 = 0.f, m1 = 0.f, v0 = 0.f, v1 = 0.f, rsc = 0.f;
    #pragma unroll
    for (int w = 0; w < 4; ++w) {
        const int base = (w * 32 + fc) * 17;
        m0 += scratch_m[base + fq];
        m1 += scratch_m[base + 8 + fq];
        v0 += scratch_v[base + fq];
        v1 += scratch_v[base + 8 + fq];
        rsc += rsum_part[w * 32 + fc];
    }
    float* ac = acc + ((size_t)pos * 32 + fc) * ASTR;
    atomicAdd(&ac[fq],          m0);
    atomicAdd(&ac[8 + fq],      m1);
    atomicAdd(&ac[16 + fq],     v0);
    atomicAdd(&ac[24 + fq],     v1);
    if (fq == 0) atomicAdd(&ac[32], rsc);
}

// ---------------- finalize: stats -> routing tabs (or outputs) ----------------
// grid 288 x 512; thread = (fc = tid>>4, fp = tid&15). Also re-zeroes acc.
template <bool LAST>
__global__ __launch_bounds__(512) void fin_kernel(
    float* __restrict__ acc,
    float* __restrict__ tabs,
    const float* __restrict__ bu,
    const float* __restrict__ ba,
    float* __restrict__ outp)
{
    const int tid = threadIdx.x, pos = blockIdx.x;
    const int fc = tid >> 4, fp = tid & 15;
    float* ac = acc + ((size_t)pos * 32 + fc) * ASTR;
    const float ms  = ac[fp];
    const float vs  = ac[16 + fp];
    const float rsc = ac[32];

    const float inv = 1.f / (rsc + 1e-6f);
    const float S   = rsc * inv;
    const float mu  = ms * inv;
    const float sig = vs * inv - mu * mu * (2.f - S) + 1e-6f;
    const float ia  = 0.5f / sig;
    const float lg  = __logf(sig);
    const float cs  = mu * mu * ia;
    float lgs = lg, ccs = cs;   // reduce over the 16 p-lanes sharing fc
    #pragma unroll
    for (int msk = 8; msk >= 1; msk >>= 1) {
        lgs += __shfl_xor(lgs, msk);
        ccs += __shfl_xor(ccs, msk);
    }
    const float cost = rsc * (16.f * bu[fc] + 0.5f * lgs);
    const float ao   = 1.f / (1.f + __expf(-0.001f * (ba[fc] - cost)));

    // re-zero acc for the next stats pass
    ac[fp] = 0.f; ac[16 + fp] = 0.f;
    if (fp == 0) ac[32] = 0.f;

    if (LAST) {
        outp[(size_t)pos * 512 + tid] = mu;                      // p_out
        if (fp == 0) outp[147456 + (size_t)pos * 32 + fc] = ao;  // a_out
    } else {
        float* tb = tabs + ((size_t)pos * 32 + fc) * ASTR;
        tb[fp]      = ia;             // A = 0.5/sigma
        tb[16 + fp] = 2.f * mu * ia;  // B = mu/sigma
        if (fp == 0) tb[32] = 0.5f * lgs - __logf(ao) + ccs;   // Kc
    }
}

extern "C" void kernel_launch(void* const* d_in, const int* in_sizes, int n_in,
                              void* d_out, int out_size, void* d_ws, size_t ws_size,
                              hipStream_t stream) {
    (void)in_sizes; (void)n_in; (void)out_size; (void)ws_size;
    const float* x  = (const float*)d_in[0];
    const float* a  = (const float*)d_in[1];
    const float* w  = (const float*)d_in[2];
    const float* bu = (const float*)d_in[3];
    const float* ba = (const float*)d_in[4];
    float* out  = (float*)d_out;
    float* acc  = (float*)d_ws;            // 288*32*33 floats = 1.22 MB
    float* tabs = acc + ACC_FLOATS;        // same size; total ws use 2.43 MB

    hipMemsetAsync(acc, 0, ACC_FLOATS * sizeof(float), stream);

    stats_kernel<true ><<<dim3(NPOS * NS), dim3(256), 0, stream>>>(x, a, w, tabs, acc);
    fin_kernel  <false><<<dim3(NPOS),      dim3(512), 0, stream>>>(acc, tabs, bu, ba, out);
    stats_kernel<false><<<dim3(NPOS * NS), dim3(256), 0, stream>>>(x, a, w, tabs, acc);
    fin_kernel  <false><<<dim3(NPOS),      dim3(512), 0, stream>>>(acc, tabs, bu, ba, out);
    stats_kernel<false><<<dim3(NPOS * NS), dim3(256), 0, stream>>>(x, a, w, tabs, acc);
    fin_kernel  <true ><<<dim3(NPOS),      dim3(512), 0, stream>>>(acc, tabs, bu, ba, out);
}